// Round 1
// baseline (325.245 us; speedup 1.0000x reference)
//
#include <hip/hip_runtime.h>
#include <math.h>

// Dims (fixed by the problem)
#define B_SZ 2
#define L_SZ 384
#define D_SZ 384
#define S_SZ 384
#define BLK_ELEMS (L_SZ * D_SZ)        // 147456 per batch
#define TOT_ELEMS (B_SZ * L_SZ * D_SZ) // 294912

__device__ __forceinline__ float fexp2(float x) {
#if __has_builtin(__builtin_amdgcn_exp2f)
  return __builtin_amdgcn_exp2f(x);
#else
  return exp2f(x);
#endif
}

__device__ __forceinline__ float softplus_f(float z) {
  return (z > 20.f) ? z : log1pf(__expf(z));
}

// ---------------------------------------------------------------------------
// Dual NT-GEMM: O1[m,n] = (softplus?)(sum_k A[m,k]*W1[n,k] + b1[n])
//               O2[m,n] =             sum_k A[m,k]*W2[n,k]
// M=768, N=384, K=384. 32x32 tile, 256 threads, 2x2 micro-tile.
// ---------------------------------------------------------------------------
template <bool SP>
__global__ __launch_bounds__(256) void dual_gemm_nt(
    const float* __restrict__ A, const float* __restrict__ W1,
    const float* __restrict__ W2, const float* __restrict__ b1,
    float* __restrict__ O1, float* __restrict__ O2) {
  __shared__ float As[32][33];
  __shared__ float B1s[32][33];
  __shared__ float B2s[32][33];

  const int tid = threadIdx.x;
  const int tx = tid & 15;        // n micro index
  const int ty = tid >> 4;        // m micro index
  const int m0 = blockIdx.y * 32;
  const int n0 = blockIdx.x * 32;
  const int lr = tid >> 3;        // staging row 0..31
  const int lc = (tid & 7) << 2;  // staging col (float4) 0..28

  float a00 = 0.f, a01 = 0.f, a10 = 0.f, a11 = 0.f;
  float c00 = 0.f, c01 = 0.f, c10 = 0.f, c11 = 0.f;

  for (int kt = 0; kt < 384; kt += 32) {
    const float4 va = *(const float4*)(A + (m0 + lr) * 384 + kt + lc);
    const float4 v1 = *(const float4*)(W1 + (n0 + lr) * 384 + kt + lc);
    const float4 v2 = *(const float4*)(W2 + (n0 + lr) * 384 + kt + lc);
    __syncthreads();  // previous compute done reading LDS
    As[lr][lc + 0] = va.x; As[lr][lc + 1] = va.y;
    As[lr][lc + 2] = va.z; As[lr][lc + 3] = va.w;
    B1s[lr][lc + 0] = v1.x; B1s[lr][lc + 1] = v1.y;
    B1s[lr][lc + 2] = v1.z; B1s[lr][lc + 3] = v1.w;
    B2s[lr][lc + 0] = v2.x; B2s[lr][lc + 1] = v2.y;
    B2s[lr][lc + 2] = v2.z; B2s[lr][lc + 3] = v2.w;
    __syncthreads();
#pragma unroll
    for (int k = 0; k < 32; k++) {
      const float x0 = As[ty][k], x1 = As[ty + 16][k];
      const float w0 = B1s[tx][k], w1 = B1s[tx + 16][k];
      const float v0 = B2s[tx][k], v1c = B2s[tx + 16][k];
      a00 = fmaf(x0, w0, a00); a01 = fmaf(x0, w1, a01);
      a10 = fmaf(x1, w0, a10); a11 = fmaf(x1, w1, a11);
      c00 = fmaf(x0, v0, c00); c01 = fmaf(x0, v1c, c01);
      c10 = fmaf(x1, v0, c10); c11 = fmaf(x1, v1c, c11);
    }
  }

  const int r0 = m0 + ty, r1 = m0 + ty + 16;
  const int q0 = n0 + tx, q1 = n0 + tx + 16;
  if constexpr (SP) {
    const float bb0 = b1[q0], bb1 = b1[q1];
    O1[r0 * 384 + q0] = softplus_f(a00 + bb0);
    O1[r0 * 384 + q1] = softplus_f(a01 + bb1);
    O1[r1 * 384 + q0] = softplus_f(a10 + bb0);
    O1[r1 * 384 + q1] = softplus_f(a11 + bb1);
  } else {
    O1[r0 * 384 + q0] = a00;
    O1[r0 * 384 + q1] = a01;
    O1[r1 * 384 + q0] = a10;
    O1[r1 * 384 + q1] = a11;
  }
  O2[r0 * 384 + q0] = c00;
  O2[r0 * 384 + q1] = c01;
  O2[r1 * 384 + q0] = c10;
  O2[r1 * 384 + q1] = c11;
}

// ---------------------------------------------------------------------------
// Causal depthwise conv (k=4, left pad 3) + bias + SiLU -> u[b,l,i]
// ---------------------------------------------------------------------------
__global__ __launch_bounds__(256) void conv_silu_kernel(
    const float* __restrict__ x, const float* __restrict__ cw,
    const float* __restrict__ cb, float* __restrict__ u) {
  const int idx = blockIdx.x * 256 + threadIdx.x;  // over B*L*D
  const int i = idx % D_SZ;
  const int l = (idx / D_SZ) % L_SZ;
  const int b = idx / BLK_ELEMS;
  float acc = cb[i];
#pragma unroll
  for (int t = 0; t < 4; t++) {
    const int ls = l - 3 + t;
    const float xv = (ls >= 0) ? x[(b * L_SZ + ls) * D_SZ + i] : 0.f;
    acc = fmaf(xv, cw[i * 4 + t], acc);
  }
  u[idx] = acc / (1.f + __expf(-acc));  // silu
}

// ---------------------------------------------------------------------------
// Selective scan: one wave per (b,i). 6 states per lane (j = lane + 64*t).
//   h[j] <- exp(dt[b,l,i]*A[i,j]) * h[j] + dt*Bm[b,i,j]*u[b,l,i]
//   y[b,l,i] = sum_j h[j]*Cm[b,l,j] + u*D[i]
// Bm row is per-(b,i) constant (reference's quirky broadcast) -> registers.
// ---------------------------------------------------------------------------
__global__ __launch_bounds__(64) void scan_kernel(
    const float* __restrict__ A_log, const float* __restrict__ Dp,
    const float* __restrict__ dt, const float* __restrict__ Bm,
    const float* __restrict__ Cm, const float* __restrict__ u,
    float* __restrict__ y) {
  const int blk = blockIdx.x;  // 0..767
  const int b = blk / D_SZ;
  const int i = blk % D_SZ;
  const int lane = threadIdx.x;  // 0..63

  float a2[6], bw[6], h[6];
#pragma unroll
  for (int t = 0; t < 6; t++) {
    const int j = lane + 64 * t;
    // A = -exp(A_log); fold log2(e) so decay = exp2(dt * a2)
    a2[t] = -__expf(A_log[i * S_SZ + j]) * 1.4426950408889634f;
    bw[t] = Bm[(b * D_SZ + i) * S_SZ + j];
    h[t] = 0.f;
  }
  const float Di = Dp[i];

  const float* dtp = dt + b * BLK_ELEMS + i;  // stride D_SZ per l
  const float* up = u + b * BLK_ELEMS + i;
  const float* cp = Cm + b * BLK_ELEMS + lane;
  float* yp = y + b * BLK_ELEMS + i;

  float dt_s = dtp[0];
  float u_s = up[0];
  float c[6];
#pragma unroll
  for (int t = 0; t < 6; t++) c[t] = cp[64 * t];

  for (int l = 0; l < L_SZ; l++) {
    // prefetch next step's operands (off the h-dependency chain)
    float dt_n = 0.f, u_n = 0.f, cn[6] = {0.f, 0.f, 0.f, 0.f, 0.f, 0.f};
    if (l < L_SZ - 1) {
      dt_n = dtp[(l + 1) * D_SZ];
      u_n = up[(l + 1) * D_SZ];
#pragma unroll
      for (int t = 0; t < 6; t++) cn[t] = cp[(l + 1) * D_SZ + 64 * t];
    }
    const float dtu = dt_s * u_s;
    float acc = 0.f;
#pragma unroll
    for (int t = 0; t < 6; t++) {
      const float e = fexp2(dt_s * a2[t]);
      h[t] = fmaf(e, h[t], bw[t] * dtu);
      acc = fmaf(h[t], c[t], acc);
    }
#pragma unroll
    for (int off = 32; off; off >>= 1) acc += __shfl_xor(acc, off, 64);
    if (lane == 0) yp[l * D_SZ] = fmaf(u_s, Di, acc);
    dt_s = dt_n;
    u_s = u_n;
#pragma unroll
    for (int t = 0; t < 6; t++) c[t] = cn[t];
  }
}

extern "C" void kernel_launch(void* const* d_in, const int* in_sizes, int n_in,
                              void* d_out, int out_size, void* d_ws,
                              size_t ws_size, hipStream_t stream) {
  const float* x = (const float*)d_in[0];
  const float* A_log = (const float*)d_in[1];
  const float* D = (const float*)d_in[2];
  const float* dt_w = (const float*)d_in[3];
  const float* dt_b = (const float*)d_in[4];
  const float* B_w = (const float*)d_in[5];
  const float* C_w = (const float*)d_in[6];
  const float* conv_w = (const float*)d_in[7];
  const float* conv_b = (const float*)d_in[8];
  float* y = (float*)d_out;

  float* ws = (float*)d_ws;
  float* dt = ws;                    // 294912
  float* xdbl = ws + TOT_ELEMS;      // 294912
  float* Bm = ws + 2 * TOT_ELEMS;    // 294912
  float* Cm = ws + 3 * TOT_ELEMS;    // 294912
  float* u = ws + 4 * TOT_ELEMS;     // 294912  (total 5.9 MB)

  const dim3 gemm_grid(D_SZ / 32, (B_SZ * L_SZ) / 32);  // 12 x 24
  dual_gemm_nt<true><<<gemm_grid, 256, 0, stream>>>(x, dt_w, B_w, dt_b, dt, xdbl);
  dual_gemm_nt<false><<<gemm_grid, 256, 0, stream>>>(xdbl, B_w, C_w, nullptr, Bm, Cm);
  conv_silu_kernel<<<TOT_ELEMS / 256, 256, 0, stream>>>(x, conv_w, conv_b, u);
  scan_kernel<<<B_SZ * D_SZ, 64, 0, stream>>>(A_log, D, dt, Bm, Cm, u, y);
}

// Round 2
// 213.178 us; speedup vs baseline: 1.5257x; 1.5257x over previous
//
#include <hip/hip_runtime.h>
#include <math.h>

// Dims (fixed by the problem)
#define B_SZ 2
#define L_SZ 384
#define D_SZ 384
#define S_SZ 384
#define BLK_ELEMS (L_SZ * D_SZ)        // 147456 per batch
#define TOT_ELEMS (B_SZ * L_SZ * D_SZ) // 294912

__device__ __forceinline__ float fexp2(float x) {
  return __builtin_amdgcn_exp2f(x);
}

__device__ __forceinline__ float softplus_f(float z) {
  return (z > 20.f) ? z : log1pf(__expf(z));
}

// ---------------------------------------------------------------------------
// DPP wave64 reduction -> full sum lands in lane 63. VALU pipe, no DS.
// ---------------------------------------------------------------------------
template <int CTRL, int RMASK>
__device__ __forceinline__ float dpp_add(float v) {
  int t = __builtin_amdgcn_update_dpp(0, __float_as_int(v), CTRL, RMASK, 0xF, true);
  return v + __int_as_float(t);
}
__device__ __forceinline__ float wave_reduce_lane63(float v) {
  v = dpp_add<0xB1, 0xF>(v);   // quad_perm [1,0,3,2]  (xor 1)
  v = dpp_add<0x4E, 0xF>(v);   // quad_perm [2,3,0,1]  (xor 2)
  v = dpp_add<0x141, 0xF>(v);  // row_half_mirror      (xor 4-ish)
  v = dpp_add<0x140, 0xF>(v);  // row_mirror           (xor 8-ish) -> row sums
  v = dpp_add<0x142, 0xA>(v);  // row_bcast15 -> rows 1,3
  v = dpp_add<0x143, 0xC>(v);  // row_bcast31 -> rows 2,3; lane63 = total
  return v;
}

// ---------------------------------------------------------------------------
// Dual NT-GEMM: O1[m,n] = (softplus?)(sum_k A[m,k]*W1[n,k] + b1[n])
//               O2[m,n] =             sum_k A[m,k]*W2[n,k]
// M=768, N=384, K=384. 64x64 tile, 256 threads, 4x4 micro-tile.
// LDS stored k-major (transposed) so fragments are ds_read_b128.
// ---------------------------------------------------------------------------
template <bool SP>
__global__ __launch_bounds__(256) void dual_gemm_nt(
    const float* __restrict__ A, const float* __restrict__ W1,
    const float* __restrict__ W2, const float* __restrict__ b1,
    float* __restrict__ O1, float* __restrict__ O2) {
  __shared__ float As[16][68];
  __shared__ float W1s[16][68];
  __shared__ float W2s[16][68];

  const int tid = threadIdx.x;
  const int tx = tid & 15;       // n micro index (4 cols each)
  const int ty = tid >> 4;       // m micro index (4 rows each)
  const int m0 = blockIdx.y * 64;
  const int n0 = blockIdx.x * 64;
  const int sm = tid >> 2;       // staging row within tile 0..63
  const int sk = (tid & 3) * 4;  // staging k quad 0,4,8,12

  float acc1[4][4] = {{0.f}};
  float acc2[4][4] = {{0.f}};

  for (int kt = 0; kt < 384; kt += 16) {
    const float4 va = *(const float4*)(A + (m0 + sm) * 384 + kt + sk);
    const float4 v1 = *(const float4*)(W1 + (n0 + sm) * 384 + kt + sk);
    const float4 v2 = *(const float4*)(W2 + (n0 + sm) * 384 + kt + sk);
    __syncthreads();  // previous compute done reading LDS
    As[sk + 0][sm] = va.x; As[sk + 1][sm] = va.y;
    As[sk + 2][sm] = va.z; As[sk + 3][sm] = va.w;
    W1s[sk + 0][sm] = v1.x; W1s[sk + 1][sm] = v1.y;
    W1s[sk + 2][sm] = v1.z; W1s[sk + 3][sm] = v1.w;
    W2s[sk + 0][sm] = v2.x; W2s[sk + 1][sm] = v2.y;
    W2s[sk + 2][sm] = v2.z; W2s[sk + 3][sm] = v2.w;
    __syncthreads();
#pragma unroll
    for (int k = 0; k < 16; ++k) {
      const float4 afv = *(const float4*)&As[k][ty * 4];
      const float4 w1v = *(const float4*)&W1s[k][tx * 4];
      const float4 w2v = *(const float4*)&W2s[k][tx * 4];
      const float af[4] = {afv.x, afv.y, afv.z, afv.w};
      const float w1[4] = {w1v.x, w1v.y, w1v.z, w1v.w};
      const float w2[4] = {w2v.x, w2v.y, w2v.z, w2v.w};
#pragma unroll
      for (int r = 0; r < 4; ++r) {
#pragma unroll
        for (int c = 0; c < 4; ++c) {
          acc1[r][c] = fmaf(af[r], w1[c], acc1[r][c]);
          acc2[r][c] = fmaf(af[r], w2[c], acc2[r][c]);
        }
      }
    }
  }

  const int mb = m0 + ty * 4;
  const int nb = n0 + tx * 4;
#pragma unroll
  for (int r = 0; r < 4; ++r) {
    float4 o1, o2;
    float* o1p = &o1.x;
    float* o2p = &o2.x;
    if constexpr (SP) {
#pragma unroll
      for (int c = 0; c < 4; ++c)
        o1p[c] = softplus_f(acc1[r][c] + b1[nb + c]);
    } else {
#pragma unroll
      for (int c = 0; c < 4; ++c) o1p[c] = acc1[r][c];
    }
#pragma unroll
    for (int c = 0; c < 4; ++c) o2p[c] = acc2[r][c];
    *(float4*)(O1 + (mb + r) * 384 + nb) = o1;
    *(float4*)(O2 + (mb + r) * 384 + nb) = o2;
  }
}

// ---------------------------------------------------------------------------
// Causal depthwise conv (k=4, left pad 3) + bias + SiLU -> u[b,l,i]
// ---------------------------------------------------------------------------
__global__ __launch_bounds__(256) void conv_silu_kernel(
    const float* __restrict__ x, const float* __restrict__ cw,
    const float* __restrict__ cb, float* __restrict__ u) {
  const int idx = blockIdx.x * 256 + threadIdx.x;  // over B*L*D
  const int i = idx % D_SZ;
  const int l = (idx / D_SZ) % L_SZ;
  const int b = idx / BLK_ELEMS;
  float acc = cb[i];
#pragma unroll
  for (int t = 0; t < 4; t++) {
    const int ls = l - 3 + t;
    const float xv = (ls >= 0) ? x[(b * L_SZ + ls) * D_SZ + i] : 0.f;
    acc = fmaf(xv, cw[i * 4 + t], acc);
  }
  u[idx] = acc / (1.f + __expf(-acc));  // silu
}

// ---------------------------------------------------------------------------
// Selective scan v2: one wave per (b,i). States j = 6*lane + t (contiguous
// per lane -> float2 C loads). Register chunk pipeline CH=4, ping-pong
// double buffer: loads for chunk k+1 stay in flight across chunk k's
// compute (~450 cyc window). Reduction via DPP on the VALU pipe.
// ---------------------------------------------------------------------------
__global__ __launch_bounds__(64) void scan_kernel(
    const float* __restrict__ A_log, const float* __restrict__ Dp,
    const float* __restrict__ dt, const float* __restrict__ Bm,
    const float* __restrict__ Cm, const float* __restrict__ u,
    float* __restrict__ y) {
  const int blk = blockIdx.x;  // 0..767
  const int b = blk / D_SZ;
  const int i = blk % D_SZ;
  const int lane = threadIdx.x;  // 0..63
  const int j0 = lane * 6;       // this lane's 6 contiguous states

  float a2[6], bw[6], h[6];
#pragma unroll
  for (int t = 0; t < 6; ++t) {
    // A = -exp(A_log); fold log2(e) so decay = exp2(dt * a2)
    a2[t] = -__expf(A_log[i * S_SZ + j0 + t]) * 1.4426950408889634f;
    bw[t] = Bm[(b * D_SZ + i) * S_SZ + j0 + t];
    h[t] = 0.f;
  }
  const float Di = Dp[i];

  const float* dtp = dt + b * BLK_ELEMS + i;   // stride D_SZ per l
  const float* up = u + b * BLK_ELEMS + i;
  const float* cp = Cm + b * BLK_ELEMS + j0;   // row l: + l*D_SZ
  float* yp = y + b * BLK_ELEMS + i;

  float ca[24], da[4], ua[4];
  float cb_[24], db[4], ub[4];

  auto load_chunk = [&](int l0, float (&c)[24], float (&d)[4], float (&uu)[4]) {
#pragma unroll
    for (int s = 0; s < 4; ++s) {
      const int l = (l0 + s < L_SZ) ? (l0 + s) : (L_SZ - 1);
      d[s] = dtp[l * D_SZ];
      uu[s] = up[l * D_SZ];
      const float* row = cp + l * D_SZ;
      const float2 p0 = *(const float2*)(row + 0);
      const float2 p1 = *(const float2*)(row + 2);
      const float2 p2 = *(const float2*)(row + 4);
      c[s * 6 + 0] = p0.x; c[s * 6 + 1] = p0.y;
      c[s * 6 + 2] = p1.x; c[s * 6 + 3] = p1.y;
      c[s * 6 + 4] = p2.x; c[s * 6 + 5] = p2.y;
    }
  };

  auto steps4 = [&](int l0, float (&c)[24], float (&d)[4], float (&uu)[4]) {
#pragma unroll
    for (int s = 0; s < 4; ++s) {
      const float dt_s = d[s], u_s = uu[s];
      const float dtu = dt_s * u_s;
      float acc = 0.f;
#pragma unroll
      for (int t = 0; t < 6; ++t) {
        const float e = fexp2(dt_s * a2[t]);
        h[t] = fmaf(e, h[t], bw[t] * dtu);
        acc = fmaf(h[t], c[s * 6 + t], acc);
      }
      acc = wave_reduce_lane63(acc);
      if (lane == 63) yp[(l0 + s) * D_SZ] = fmaf(u_s, Di, acc);
    }
  };

  load_chunk(0, ca, da, ua);
  for (int cc = 0; cc < 48; ++cc) {
    const int l0 = cc * 8;
    load_chunk(l0 + 4, cb_, db, ub);  // prefetch while computing ca
    steps4(l0, ca, da, ua);
    load_chunk(l0 + 8, ca, da, ua);   // prefetch (clamped on last iter)
    steps4(l0 + 4, cb_, db, ub);
  }
}

extern "C" void kernel_launch(void* const* d_in, const int* in_sizes, int n_in,
                              void* d_out, int out_size, void* d_ws,
                              size_t ws_size, hipStream_t stream) {
  const float* x = (const float*)d_in[0];
  const float* A_log = (const float*)d_in[1];
  const float* D = (const float*)d_in[2];
  const float* dt_w = (const float*)d_in[3];
  const float* dt_b = (const float*)d_in[4];
  const float* B_w = (const float*)d_in[5];
  const float* C_w = (const float*)d_in[6];
  const float* conv_w = (const float*)d_in[7];
  const float* conv_b = (const float*)d_in[8];
  float* y = (float*)d_out;

  float* ws = (float*)d_ws;
  float* dt = ws;                    // 294912
  float* xdbl = ws + TOT_ELEMS;      // 294912
  float* Bm = ws + 2 * TOT_ELEMS;    // 294912
  float* Cm = ws + 3 * TOT_ELEMS;    // 294912
  float* u = ws + 4 * TOT_ELEMS;     // 294912  (total 5.9 MB)

  const dim3 gemm_grid(D_SZ / 64, (B_SZ * L_SZ) / 64);  // 6 x 12
  dual_gemm_nt<true><<<gemm_grid, 256, 0, stream>>>(x, dt_w, B_w, dt_b, dt, xdbl);
  dual_gemm_nt<false><<<gemm_grid, 256, 0, stream>>>(xdbl, B_w, C_w, nullptr, Bm, Cm);
  conv_silu_kernel<<<TOT_ELEMS / 256, 256, 0, stream>>>(x, conv_w, conv_b, u);
  scan_kernel<<<B_SZ * D_SZ, 64, 0, stream>>>(A_log, D, dt, Bm, Cm, u, y);
}